// Round 12
// baseline (646.114 us; speedup 1.0000x reference)
//
#include <hip/hip_runtime.h>
#include <hip/hip_bf16.h>

#define WST 184   // wbuf row stride in f16 (176 + 8 pad)
#define CROW 264  // cbuf row stride in f16 units (512B lane chunks + 16B ea)

typedef __attribute__((ext_vector_type(8))) short bf16x8;
typedef __attribute__((ext_vector_type(4))) float f32x4;

__device__ inline ushort f2bf(float f){
  union { __hip_bfloat16 b; ushort u; } v;
  v.b = __float2bfloat16(f);
  return v.u;
}
__device__ inline ushort f2h(float f){ _Float16 h=(_Float16)f; ushort u; __builtin_memcpy(&u,&h,2); return u; }
__device__ inline float h2f(ushort u){ _Float16 h; __builtin_memcpy(&h,&u,2); return (float)h; }

// ---------- K1: node transforms (64 nodes / block) ----------
__global__ __launch_bounds__(256) void k_node(
  const float* __restrict__ ni,
  const float* __restrict__ wss, const float* __restrict__ wsv,
  const float* __restrict__ wds, const float* __restrict__ wdv,
  float* __restrict__ xs_s, float* __restrict__ xs_d,
  float* __restrict__ xv_s, float* __restrict__ xv_d, int N)
{
  __shared__ float sW0[64*64], sW1[64*64];
  __shared__ float sV0[256], sV1[256];
  __shared__ float sRow[4][112];
  int t = threadIdx.x, wid = t>>6, lane = t&63;
  for(int i=t;i<4096;i+=256){ sW0[i]=wss[i]; sW1[i]=wds[i]; }
  if(t<256){ sV0[t]=wsv[t]; sV1[t]=wdv[t]; }
  __syncthreads();
  for(int itn=0; itn<16; ++itn){
    int node = blockIdx.x*64 + itn*4 + wid;
    if(node>=N) continue;
    const float* row = ni + (size_t)node*112;
    if(lane<56) ((float2*)sRow[wid])[lane] = ((const float2*)row)[lane];
    float* r = sRow[wid];
    float a0=0.f, a1=0.f;
    #pragma unroll 8
    for(int k=0;k<64;k++){ float x=r[k]; a0+=x*sW0[k*64+lane]; a1+=x*sW1[k*64+lane]; }
    xs_s[(size_t)node*64+lane]=a0; xs_d[(size_t)node*64+lane]=a1;
    if(lane<48){
      int e_=lane/3, d_=lane-e_*3; float b0=0.f, b1=0.f;
      #pragma unroll
      for(int c=0;c<16;c++){ float x=r[64+c*3+d_]; b0+=x*sV0[c*16+e_]; b1+=x*sV1[c*16+e_]; }
      xv_s[(size_t)node*48+lane]=b0; xv_d[(size_t)node*48+lane]=b1;
    }
  }
}

// ---------- CSR build ----------
__global__ void k_deg(const int* __restrict__ edst, int* __restrict__ deg, int E){
  int e = blockIdx.x*256 + threadIdx.x;
  if(e<E) atomicAdd(&deg[edst[e]], 1);
}

__global__ __launch_bounds__(256) void k_scan1(
  const int* __restrict__ deg, int* __restrict__ cur, int* __restrict__ bsum, int N)
{
  __shared__ int sb[256];
  int t = threadIdx.x, i = blockIdx.x*256 + t;
  int x = (i<N) ? deg[i] : 0;
  sb[t]=x; __syncthreads();
  int v=x;
  #pragma unroll
  for(int o=1;o<256;o<<=1){
    int u=(t>=o)?sb[t-o]:0; __syncthreads();
    v+=u; sb[t]=v; __syncthreads();
  }
  if(i<N) cur[i]=v-x;
  if(t==255) bsum[blockIdx.x]=v;
}

__global__ __launch_bounds__(256) void k_scan2(
  int* __restrict__ bsum, int* __restrict__ offs, int N, int nb)
{
  __shared__ int sb[256];
  int t = threadIdx.x;
  int x = (t<nb) ? bsum[t] : 0;
  sb[t]=x; __syncthreads();
  int v=x;
  #pragma unroll
  for(int o=1;o<256;o<<=1){
    int u=(t>=o)?sb[t-o]:0; __syncthreads();
    v+=u; sb[t]=v; __syncthreads();
  }
  if(t<nb) bsum[t]=v-x;
  if(t==nb-1) offs[N]=v;
}

__global__ void k_scan3(const int* __restrict__ bsum,
                        int* __restrict__ offs, int* __restrict__ cur, int N)
{
  int i = blockIdx.x*256 + threadIdx.x;
  if(i<N){ int v = cur[i] + bsum[blockIdx.x]; offs[i]=v; cur[i]=v; }
}

// fill: pos map + CSR-ordered src/dst/edge_attr
__global__ void k_fill(const int* __restrict__ esrc, const int* __restrict__ edst,
                       const float* __restrict__ eattr, int* __restrict__ cur,
                       int* __restrict__ pos_of, int* __restrict__ srcC,
                       int* __restrict__ dstC, float4* __restrict__ eaC, int E){
  int e = blockIdx.x*256 + threadIdx.x;
  if(e<E){
    int p = atomicAdd(&cur[edst[e]], 1);
    pos_of[e] = p;
    srcC[p] = esrc[e];
    dstC[p] = edst[e];
    eaC[p] = *(const float4*)&eattr[(size_t)e*4];
  }
}

// ---------- K2: radial MLP (MFMA), scatter rows to CSR slots ----------
__global__ __launch_bounds__(256) void k_mlp(
  const float* __restrict__ escal,
  const float* __restrict__ w1, const float* __restrict__ b1,
  const float* __restrict__ w2, const float* __restrict__ b2,
  const int* __restrict__ pos_of,
  _Float16* __restrict__ wbuf, int E)
{
  __shared__ __align__(16) ushort sW1t[64*136];
  __shared__ __align__(16) ushort sW2t[176*72];
  __shared__ __align__(16) ushort ubuf[4][16*WST];
  int t = threadIdx.x, wid = t>>6, lane = t&63;
  int r16 = lane&15, g = lane>>4;

  for(int i=t;i<128*64;i+=256){ int k=i>>6, n=i&63; sW1t[n*136+k]=f2bf(w1[i]); }
  for(int i=t;i<64*176;i+=256){ int k=i/176, n=i-k*176; sW2t[n*72+k]=f2bf(w2[i]); }
  __syncthreads();

  float b1v[4], b2v[11];
  #pragma unroll
  for(int nt=0;nt<4;nt++) b1v[nt]=b1[nt*16+r16];
  #pragma unroll
  for(int s=0;s<11;s++) b2v[s]=b2[s*16+r16];

  ushort* ub = ubuf[wid];
  _Float16* wsb = (_Float16*)ub;

  int ntiles = (E+15)>>4;
  int nw = gridDim.x*4;

  for(int wt = blockIdx.x*4+wid; wt < ntiles; wt += nw){
    int ebase = wt*16;
    int erow = ebase + r16; if(erow >= E) erow = E-1;

    f32x4 acc[4];
    #pragma unroll
    for(int nt=0;nt<4;nt++) acc[nt]=(f32x4){0,0,0,0};
    #pragma unroll
    for(int ks=0;ks<4;ks++){
      const float* p = escal + (size_t)erow*128 + ks*32 + g*8;
      float4 va = *(const float4*)p;
      float4 vb = *(const float4*)(p+4);
      bf16x8 af;
      af[0]=(short)f2bf(va.x); af[1]=(short)f2bf(va.y);
      af[2]=(short)f2bf(va.z); af[3]=(short)f2bf(va.w);
      af[4]=(short)f2bf(vb.x); af[5]=(short)f2bf(vb.y);
      af[6]=(short)f2bf(vb.z); af[7]=(short)f2bf(vb.w);
      #pragma unroll
      for(int nt=0;nt<4;nt++){
        bf16x8 bf = *(const bf16x8*)&sW1t[(nt*16+r16)*136 + ks*32 + g*8];
        acc[nt] = __builtin_amdgcn_mfma_f32_16x16x32_bf16(af,bf,acc[nt],0,0,0);
      }
    }

    #pragma unroll
    for(int nt=0;nt<4;nt++)
      #pragma unroll
      for(int q=0;q<4;q++) acc[nt][q] += b1v[nt];
    #pragma unroll
    for(int q=0;q<4;q++){
      float s = acc[0][q]+acc[1][q]+acc[2][q]+acc[3][q];
      float ss = acc[0][q]*acc[0][q]+acc[1][q]*acc[1][q]+acc[2][q]*acc[2][q]+acc[3][q]*acc[3][q];
      #pragma unroll
      for(int o=1;o<16;o<<=1){ s += __shfl_xor(s,o); ss += __shfl_xor(ss,o); }
      float m = s*(1.f/64.f);
      float var = ss*(1.f/64.f) - m*m;
      float inv = rsqrtf(var + 1e-5f);
      int rr = g*4+q;
      #pragma unroll
      for(int nt=0;nt<4;nt++){
        float xn = (acc[nt][q]-m)*inv;
        float h = xn/(1.f+__expf(-xn));
        ub[rr*72 + nt*16 + r16] = f2bf(h);
      }
    }

    bf16x8 af2[2];
    af2[0] = *(const bf16x8*)&ub[r16*72 + 0*32 + g*8];
    af2[1] = *(const bf16x8*)&ub[r16*72 + 1*32 + g*8];
    f32x4 c2[11];
    #pragma unroll
    for(int s=0;s<11;s++) c2[s]=(f32x4){0,0,0,0};
    #pragma unroll
    for(int ks=0;ks<2;ks++){
      #pragma unroll
      for(int s=0;s<11;s++){
        bf16x8 bf = *(const bf16x8*)&sW2t[(s*16+r16)*72 + ks*32 + g*8];
        c2[s] = __builtin_amdgcn_mfma_f32_16x16x32_bf16(af2[ks],bf,c2[s],0,0,0);
      }
    }
    #pragma unroll
    for(int s=0;s<11;s++){
      int col = s*16 + r16;
      #pragma unroll
      for(int q=0;q<4;q++){
        wsb[(g*4+q)*WST + col] = (_Float16)(c2[s][q] + b2v[s]);
      }
    }
    // scatter rows to CSR slots
    int pv = 0;
    if(lane<16 && ebase+lane < E) pv = pos_of[ebase+lane];
    int rows = E - ebase; if(rows > 16) rows = 16;
    const float4* srcv = (const float4*)ub;
    int tot4 = rows*23;   // WST/8 float4 per row
    for(int i=lane; i<tot4; i+=64){
      int r = i/23, c = i - 23*r;
      int pos = __shfl(pv, r);
      ((float4*)(wbuf + (size_t)pos*WST))[c] = srcv[i];
    }
  }
}

// ---------- K3: geometric phase, CSR-sequential, shuffle-based ----------
// ck: x=ws1, y=(lane<48)?w2v_pre:0, z=scA, w=(lane<48)?cross_pre:scB[lane-48]
__global__ __launch_bounds__(256) void k_geo(
  const int* __restrict__ srcC, const int* __restrict__ dstC,
  const float4* __restrict__ eaC, const _Float16* __restrict__ wbuf,
  const float* __restrict__ adot,
  const float* __restrict__ xs_s, const float* __restrict__ xs_d,
  const float* __restrict__ xv_s, const float* __restrict__ xv_d,
  _Float16* __restrict__ cbuf, float* __restrict__ alphaC, int E)
{
  __shared__ float sAdot[80];
  __shared__ float sP[4][80];
  int t = threadIdx.x, wid = t>>6, lane = t&63;
  if(t<80) sAdot[t]=adot[t];
  __syncthreads();

  float* P = sP[wid];
  int nw = gridDim.x*4;
  const float inv_s3 = 0.5773502691896258f, inv_s2 = 0.7071067811865475f;

  int l3 = lane/3;
  int d  = lane - l3*3;
  int k3 = l3*3;
  int d1 = (d==2)?0:d+1;
  int d2 = (d==0)?2:d-1;
  int l3c = l3&15;                 // clamped for uniform loads
  int sA = (lane*3)&63, sB = (lane*3+1)&63, sC = (lane*3+2)&63;
  int cs1 = (k3+d1)&63, cs2 = (k3+d2)&63;
  int hh5 = (lane>>1)&7, st5 = hh5*10 + (lane&1)*5;
  float adl = sAdot[lane];
  float ad2 = sAdot[64+(lane&15)];

  for(int p = blockIdx.x*4+wid; p < E; p += nw){
    int si = srcC[p], di = dstC[p];
    float4 ea = eaC[p];
    const _Float16* wr = wbuf + (size_t)p*WST;
    float S = xs_s[(size_t)si*64+lane] + xs_d[(size_t)di*64+lane];
    float Vl = (lane<48) ? (xv_s[(size_t)si*48+lane] + xv_d[(size_t)di*48+lane]) : 0.f;
    float w0 = (float)wr[lane];
    float w1v = (float)wr[64+lane];
    float sc = w0*S*ea.x;
    float sg = 1.f/(1.f+__expf(-sc));
    P[lane] = sc*(0.2f + 0.8f*sg)*adl;
    // vd3/sc2 computed branchlessly (valid where used)
    float v0=__shfl(Vl,sA), v1=__shfl(Vl,sB), v2=__shfl(Vl,sC);
    float vd3 = v0*ea.y + v1*ea.z + v2*ea.w;
    float sc2 = (float)wr[144+(lane&15)]*vd3*inv_s3;
    if(lane<16){
      float sg2 = 1.f/(1.f+__expf(-sc2));
      P[64+lane] = sc2*(0.2f + 0.8f*sg2)*ad2;
    }
    // parallel head-sum: each lane sums 5, lanes<8 combine
    float s5 = P[st5] + P[st5+1] + P[st5+2] + P[st5+3] + P[st5+4];
    float aL = __shfl(s5, 2*(lane&7)) + __shfl(s5, 2*(lane&7)+1);
    if(lane<8) alphaC[(size_t)p*8+lane] = aL;
    // scB broadcast (full exec)
    float scBv = __shfl(sc2, lane&15);
    // pre-multiplied value components
    float Vd1 = __shfl(Vl, cs1), Vd2 = __shfl(Vl, cs2);
    float wslot = scBv;
    if(lane<48){
      float e1d1 = (d1==0)?ea.y:((d1==1)?ea.z:ea.w);
      float e1d2 = (d2==0)?ea.y:((d2==1)?ea.z:ea.w);
      float cr = Vd1*e1d2 - Vd2*e1d1;
      wslot = (float)wr[160+l3c]*cr*inv_s2;
    }
    float w2v_pre = (lane<48) ? (float)wr[128+l3c]*ea.x*Vl : 0.f;
    ushort4 ck;
    ck.x = f2h(w1v*S);
    ck.y = f2h(w2v_pre);
    ck.z = f2h(sc);
    ck.w = f2h(wslot);
    _Float16* cr_ = cbuf + (size_t)p*CROW;
    *(ushort4*)(cr_ + (size_t)lane*4) = ck;
    if(lane==0) *(float4*)((char*)cr_ + 512) = ea;
  }
}

// ---------- K4: softmax + aggregation + fused projections ----------
// pass 1.5 converts alphaC rows to ev in place -> pass 2 is pure loads+FMA
#define EDGE_PROC(b, ck_, ea_, w1x,w1y,w1z,sc,aa,xx) { \
  const float* ar_ = alphaC + (size_t)(b)*8; \
  float evW1_ = ar_[hW1], evSC_ = ar_[hSC], evA_ = ar_[hA], evX_ = ar_[hX]; \
  float ws1_ = h2f(ck_.x), scA_ = h2f(ck_.z), wv_ = h2f(ck_.w); \
  float vA_ = (lane<48) ? h2f(ck_.y) : wv_; \
  float t1_ = evW1_*ws1_; \
  w1x += t1_*ea_.y; w1y += t1_*ea_.z; w1z += t1_*ea_.w; \
  sc += evSC_*scA_; aa += evA_*vA_; xx += evX_*wv_; }

__global__ __launch_bounds__(256) void k_agg(
  const int* __restrict__ offs, float* __restrict__ alphaC,
  const _Float16* __restrict__ cbuf,
  const float* __restrict__ pws, const float* __restrict__ pbs,
  const float* __restrict__ pwv, float* __restrict__ out, int N)
{
  __shared__ float sVa[4][288];
  __shared__ float sSa[4][80];
  int t=threadIdx.x, wid=t>>6, lane=t&63;

  float* Va = sVa[wid];
  float* Sa = sSa[wid];

  int l3 = lane/3;
  int d  = lane - l3*3;
  int hW1 = lane/12;
  int hX  = (80+l3)/12;
  int hSC = lane/10;
  int hA  = (lane<48) ? (64+l3)/12 : (64+(lane-48))/10;
  int h8 = lane&7;

  int nw4 = gridDim.x*4;
  for(int n = blockIdx.x*4+wid; n < N; n += nw4){
    int s0 = offs[n], s1 = offs[n+1];

    // pass 1: per-head max (lane l holds max of head l&7)
    float mx = -1e30f;
    for(int b = s0 + (lane>>3); b < s1; b += 8)
      mx = fmaxf(mx, alphaC[(size_t)b*8 + h8]);
    mx = fmaxf(mx, __shfl_xor(mx, 8));
    mx = fmaxf(mx, __shfl_xor(mx, 16));
    mx = fmaxf(mx, __shfl_xor(mx, 32));

    // pass 1.5: exp in place + den (8 exps per edge wave-wide)
    float dn = 0.f;
    for(int b = s0 + (lane>>3); b < s1; b += 8){
      size_t ix = (size_t)b*8 + h8;
      float ev = __expf(alphaC[ix] - mx);
      alphaC[ix] = ev;
      dn += ev;
    }
    dn += __shfl_xor(dn, 8);
    dn += __shfl_xor(dn, 16);
    dn += __shfl_xor(dn, 32);
    float rdn = 1.0f/(dn + 1e-9f);   // lane l: 1/den of head l&7
    float rW1 = __shfl(rdn, hW1);
    float rSC = __shfl(rdn, hSC);
    float rA  = __shfl(rdn, hA);
    float rX  = __shfl(rdn, hX);

    // pass 2: 4x-unrolled, 2 accumulator sets, pure FMA
    float w1xA=0.f,w1yA=0.f,w1zA=0.f,scAc=0.f,aaA=0.f,xxA=0.f;
    float w1xB=0.f,w1yB=0.f,w1zB=0.f,scBc=0.f,aaB=0.f,xxB=0.f;
    int b = s0;
    for(; b+3 < s1; b += 4){
      const _Float16* c0 = cbuf + (size_t)(b  )*CROW;
      const _Float16* c1 = cbuf + (size_t)(b+1)*CROW;
      const _Float16* c2 = cbuf + (size_t)(b+2)*CROW;
      const _Float16* c3 = cbuf + (size_t)(b+3)*CROW;
      ushort4 k0 = *(const ushort4*)(c0 + (size_t)lane*4);
      ushort4 k1 = *(const ushort4*)(c1 + (size_t)lane*4);
      ushort4 k2 = *(const ushort4*)(c2 + (size_t)lane*4);
      ushort4 k3v= *(const ushort4*)(c3 + (size_t)lane*4);
      float4 e0 = *(const float4*)((const char*)c0 + 512);
      float4 e1 = *(const float4*)((const char*)c1 + 512);
      float4 e2 = *(const float4*)((const char*)c2 + 512);
      float4 e3 = *(const float4*)((const char*)c3 + 512);
      EDGE_PROC(b,   k0, e0, w1xA,w1yA,w1zA,scAc,aaA,xxA)
      EDGE_PROC(b+1, k1, e1, w1xB,w1yB,w1zB,scBc,aaB,xxB)
      EDGE_PROC(b+2, k2, e2, w1xA,w1yA,w1zA,scAc,aaA,xxA)
      EDGE_PROC(b+3, k3v,e3, w1xB,w1yB,w1zB,scBc,aaB,xxB)
    }
    for(; b < s1; ++b){
      const _Float16* c0 = cbuf + (size_t)b*CROW;
      ushort4 k0 = *(const ushort4*)(c0 + (size_t)lane*4);
      float4 e0 = *(const float4*)((const char*)c0 + 512);
      EDGE_PROC(b, k0, e0, w1xA,w1yA,w1zA,scAc,aaA,xxA)
    }
    float w1x=w1xA+w1xB, w1y=w1yA+w1yB, w1z=w1zA+w1zB;
    float sc=scAc+scBc, aa=aaA+aaB, xx=xxA+xxB;

    Va[lane*3+0] = w1x*rW1;
    Va[lane*3+1] = w1y*rW1;
    Va[lane*3+2] = w1z*rW1;
    if(lane<48){
      Va[192+lane] = aa*rA;
      Va[240+lane] = xx*rX;
    } else {
      Sa[64+(lane-48)] = aa*rA;
    }
    Sa[lane] = sc*rSC;

    // fused projections (weights from global; L1-resident)
    float o1 = pbs[lane];
    #pragma unroll 8
    for(int i=0;i<80;i++) o1 += Sa[i]*pws[i*64+lane];
    out[(size_t)n*112+lane] = o1;
    if(lane<48){
      float o2 = 0.f;
      #pragma unroll 8
      for(int k=0;k<64;k++) o2 += Va[k*3+d]*pwv[k*16+l3];
      #pragma unroll
      for(int k=0;k<16;k++) o2 += Va[192+k*3+d]*pwv[(64+k)*16+l3];
      #pragma unroll
      for(int k=0;k<16;k++) o2 += Va[240+k*3+d]*pwv[(80+k)*16+l3];
      out[(size_t)n*112+64+lane] = o2;
    }
  }
}

extern "C" void kernel_launch(void* const* d_in, const int* in_sizes, int n_in,
                              void* d_out, int out_size, void* d_ws, size_t ws_size,
                              hipStream_t stream)
{
  const int N = in_sizes[0]/112;
  const int E = in_sizes[1];
  const float* ni    = (const float*)d_in[0];
  const int*   esrc  = (const int*)d_in[1];
  const int*   edst  = (const int*)d_in[2];
  const float* eattr = (const float*)d_in[3];
  const float* escal = (const float*)d_in[4];
  const float* wss   = (const float*)d_in[5];
  const float* wsv   = (const float*)d_in[6];
  const float* wds   = (const float*)d_in[7];
  const float* wdv   = (const float*)d_in[8];
  const float* rw1   = (const float*)d_in[9];
  const float* rb1   = (const float*)d_in[10];
  const float* rw2   = (const float*)d_in[11];
  const float* rb2   = (const float*)d_in[12];
  const float* adot  = (const float*)d_in[13];
  const float* pws   = (const float*)d_in[14];
  const float* pbs   = (const float*)d_in[15];
  const float* pwv   = (const float*)d_in[16];
  float* out = (float*)d_out;

  char* ws = (char*)d_ws;
  size_t off = 0;
  auto alloc = [&](size_t bytes)->void*{
    void* p = ws + off;
    off = (off + bytes + 255) & ~(size_t)255;
    return p;
  };
  float*    xs_s  = (float*)   alloc((size_t)N*64*4);
  float*    xs_d  = (float*)   alloc((size_t)N*64*4);
  float*    xv_s  = (float*)   alloc((size_t)N*48*4);
  float*    xv_d  = (float*)   alloc((size_t)N*48*4);
  _Float16* wbuf  = (_Float16*)alloc((size_t)E*WST*2);
  _Float16* cbuf  = (_Float16*)alloc((size_t)E*CROW*2);
  float*    alphaC= (float*)   alloc((size_t)E*8*4);
  int*      pos_of= (int*)     alloc((size_t)E*4);
  int*      srcC  = (int*)     alloc((size_t)E*4);
  int*      dstC  = (int*)     alloc((size_t)E*4);
  float4*   eaC   = (float4*)  alloc((size_t)E*16);
  int*      deg   = (int*)     alloc((size_t)N*4);
  int*      offs  = (int*)     alloc((size_t)(N+1)*4);
  int*      cur   = (int*)     alloc((size_t)N*4);
  int*      bsum  = (int*)     alloc(256*4);

  const int nb = (N+255)/256;

  hipMemsetAsync(deg, 0, (size_t)N*4, stream);

  k_node<<<(N+63)/64, 256, 0, stream>>>(ni, wss, wsv, wds, wdv, xs_s, xs_d, xv_s, xv_d, N);
  k_deg<<<(E+255)/256, 256, 0, stream>>>(edst, deg, E);
  k_scan1<<<nb, 256, 0, stream>>>(deg, cur, bsum, N);
  k_scan2<<<1, 256, 0, stream>>>(bsum, offs, N, nb);
  k_scan3<<<nb, 256, 0, stream>>>(bsum, offs, cur, N);
  k_fill<<<(E+255)/256, 256, 0, stream>>>(esrc, edst, eattr, cur, pos_of, srcC, dstC, eaC, E);

  k_mlp<<<512, 256, 0, stream>>>(escal, rw1, rb1, rw2, rb2, pos_of, wbuf, E);

  k_geo<<<2048, 256, 0, stream>>>(srcC, dstC, eaC, wbuf, adot,
        xs_s, xs_d, xv_s, xv_d, cbuf, alphaC, E);

  k_agg<<<2048, 256, 0, stream>>>(offs, alphaC, cbuf, pws, pbs, pwv, out, N);
}

// Round 13
// 546.300 us; speedup vs baseline: 1.1827x; 1.1827x over previous
//
#include <hip/hip_runtime.h>
#include <hip/hip_bf16.h>

#define WST 184   // wbuf row stride in f16 (176 + 8 pad)
#define CROW 264  // cbuf row stride in f16 units (512B lane chunks + 16B ea)

typedef __attribute__((ext_vector_type(8))) short bf16x8;
typedef __attribute__((ext_vector_type(4))) float f32x4;

__device__ inline ushort f2bf(float f){
  union { __hip_bfloat16 b; ushort u; } v;
  v.b = __float2bfloat16(f);
  return v.u;
}
__device__ inline ushort f2h(float f){ _Float16 h=(_Float16)f; ushort u; __builtin_memcpy(&u,&h,2); return u; }
__device__ inline float h2f(ushort u){ _Float16 h; __builtin_memcpy(&h,&u,2); return (float)h; }

// ---------- K1: node transforms (64 nodes / block) ----------
__global__ __launch_bounds__(256) void k_node(
  const float* __restrict__ ni,
  const float* __restrict__ wss, const float* __restrict__ wsv,
  const float* __restrict__ wds, const float* __restrict__ wdv,
  float* __restrict__ xs_s, float* __restrict__ xs_d,
  float* __restrict__ xv_s, float* __restrict__ xv_d, int N)
{
  __shared__ float sW0[64*64], sW1[64*64];
  __shared__ float sV0[256], sV1[256];
  __shared__ float sRow[4][112];
  int t = threadIdx.x, wid = t>>6, lane = t&63;
  for(int i=t;i<4096;i+=256){ sW0[i]=wss[i]; sW1[i]=wds[i]; }
  if(t<256){ sV0[t]=wsv[t]; sV1[t]=wdv[t]; }
  __syncthreads();
  for(int itn=0; itn<16; ++itn){
    int node = blockIdx.x*64 + itn*4 + wid;
    if(node>=N) continue;
    const float* row = ni + (size_t)node*112;
    if(lane<56) ((float2*)sRow[wid])[lane] = ((const float2*)row)[lane];
    float* r = sRow[wid];
    float a0=0.f, a1=0.f;
    #pragma unroll 8
    for(int k=0;k<64;k++){ float x=r[k]; a0+=x*sW0[k*64+lane]; a1+=x*sW1[k*64+lane]; }
    xs_s[(size_t)node*64+lane]=a0; xs_d[(size_t)node*64+lane]=a1;
    if(lane<48){
      int e_=lane/3, d_=lane-e_*3; float b0=0.f, b1=0.f;
      #pragma unroll
      for(int c=0;c<16;c++){ float x=r[64+c*3+d_]; b0+=x*sV0[c*16+e_]; b1+=x*sV1[c*16+e_]; }
      xv_s[(size_t)node*48+lane]=b0; xv_d[(size_t)node*48+lane]=b1;
    }
  }
}

// ---------- CSR build ----------
__global__ void k_deg(const int* __restrict__ edst, int* __restrict__ deg, int E){
  int e = blockIdx.x*256 + threadIdx.x;
  if(e<E) atomicAdd(&deg[edst[e]], 1);
}

__global__ __launch_bounds__(256) void k_scan1(
  const int* __restrict__ deg, int* __restrict__ cur, int* __restrict__ bsum, int N)
{
  __shared__ int sb[256];
  int t = threadIdx.x, i = blockIdx.x*256 + t;
  int x = (i<N) ? deg[i] : 0;
  sb[t]=x; __syncthreads();
  int v=x;
  #pragma unroll
  for(int o=1;o<256;o<<=1){
    int u=(t>=o)?sb[t-o]:0; __syncthreads();
    v+=u; sb[t]=v; __syncthreads();
  }
  if(i<N) cur[i]=v-x;
  if(t==255) bsum[blockIdx.x]=v;
}

__global__ __launch_bounds__(256) void k_scan2(
  int* __restrict__ bsum, int* __restrict__ offs, int N, int nb)
{
  __shared__ int sb[256];
  int t = threadIdx.x;
  int x = (t<nb) ? bsum[t] : 0;
  sb[t]=x; __syncthreads();
  int v=x;
  #pragma unroll
  for(int o=1;o<256;o<<=1){
    int u=(t>=o)?sb[t-o]:0; __syncthreads();
    v+=u; sb[t]=v; __syncthreads();
  }
  if(t<nb) bsum[t]=v-x;
  if(t==nb-1) offs[N]=v;
}

__global__ void k_scan3(const int* __restrict__ bsum,
                        int* __restrict__ offs, int* __restrict__ cur, int N)
{
  int i = blockIdx.x*256 + threadIdx.x;
  if(i<N){ int v = cur[i] + bsum[blockIdx.x]; offs[i]=v; cur[i]=v; }
}

// fill: pos map + CSR-ordered src/dst/edge_attr
__global__ void k_fill(const int* __restrict__ esrc, const int* __restrict__ edst,
                       const float* __restrict__ eattr, int* __restrict__ cur,
                       int* __restrict__ pos_of, int* __restrict__ srcC,
                       int* __restrict__ dstC, float4* __restrict__ eaC, int E){
  int e = blockIdx.x*256 + threadIdx.x;
  if(e<E){
    int p = atomicAdd(&cur[edst[e]], 1);
    pos_of[e] = p;
    srcC[p] = esrc[e];
    dstC[p] = edst[e];
    eaC[p] = *(const float4*)&eattr[(size_t)e*4];
  }
}

// ---------- K2: radial MLP (MFMA), scatter rows to CSR slots ----------
__global__ __launch_bounds__(256) void k_mlp(
  const float* __restrict__ escal,
  const float* __restrict__ w1, const float* __restrict__ b1,
  const float* __restrict__ w2, const float* __restrict__ b2,
  const int* __restrict__ pos_of,
  _Float16* __restrict__ wbuf, int E)
{
  __shared__ __align__(16) ushort sW1t[64*136];
  __shared__ __align__(16) ushort sW2t[176*72];
  __shared__ __align__(16) ushort ubuf[4][16*WST];
  int t = threadIdx.x, wid = t>>6, lane = t&63;
  int r16 = lane&15, g = lane>>4;

  for(int i=t;i<128*64;i+=256){ int k=i>>6, n=i&63; sW1t[n*136+k]=f2bf(w1[i]); }
  for(int i=t;i<64*176;i+=256){ int k=i/176, n=i-k*176; sW2t[n*72+k]=f2bf(w2[i]); }
  __syncthreads();

  float b1v[4], b2v[11];
  #pragma unroll
  for(int nt=0;nt<4;nt++) b1v[nt]=b1[nt*16+r16];
  #pragma unroll
  for(int s=0;s<11;s++) b2v[s]=b2[s*16+r16];

  ushort* ub = ubuf[wid];
  _Float16* wsb = (_Float16*)ub;

  int ntiles = (E+15)>>4;
  int nw = gridDim.x*4;

  for(int wt = blockIdx.x*4+wid; wt < ntiles; wt += nw){
    int ebase = wt*16;
    int erow = ebase + r16; if(erow >= E) erow = E-1;

    f32x4 acc[4];
    #pragma unroll
    for(int nt=0;nt<4;nt++) acc[nt]=(f32x4){0,0,0,0};
    #pragma unroll
    for(int ks=0;ks<4;ks++){
      const float* p = escal + (size_t)erow*128 + ks*32 + g*8;
      float4 va = *(const float4*)p;
      float4 vb = *(const float4*)(p+4);
      bf16x8 af;
      af[0]=(short)f2bf(va.x); af[1]=(short)f2bf(va.y);
      af[2]=(short)f2bf(va.z); af[3]=(short)f2bf(va.w);
      af[4]=(short)f2bf(vb.x); af[5]=(short)f2bf(vb.y);
      af[6]=(short)f2bf(vb.z); af[7]=(short)f2bf(vb.w);
      #pragma unroll
      for(int nt=0;nt<4;nt++){
        bf16x8 bf = *(const bf16x8*)&sW1t[(nt*16+r16)*136 + ks*32 + g*8];
        acc[nt] = __builtin_amdgcn_mfma_f32_16x16x32_bf16(af,bf,acc[nt],0,0,0);
      }
    }

    #pragma unroll
    for(int nt=0;nt<4;nt++)
      #pragma unroll
      for(int q=0;q<4;q++) acc[nt][q] += b1v[nt];
    #pragma unroll
    for(int q=0;q<4;q++){
      float s = acc[0][q]+acc[1][q]+acc[2][q]+acc[3][q];
      float ss = acc[0][q]*acc[0][q]+acc[1][q]*acc[1][q]+acc[2][q]*acc[2][q]+acc[3][q]*acc[3][q];
      #pragma unroll
      for(int o=1;o<16;o<<=1){ s += __shfl_xor(s,o); ss += __shfl_xor(ss,o); }
      float m = s*(1.f/64.f);
      float var = ss*(1.f/64.f) - m*m;
      float inv = rsqrtf(var + 1e-5f);
      int rr = g*4+q;
      #pragma unroll
      for(int nt=0;nt<4;nt++){
        float xn = (acc[nt][q]-m)*inv;
        float h = xn/(1.f+__expf(-xn));
        ub[rr*72 + nt*16 + r16] = f2bf(h);
      }
    }

    bf16x8 af2[2];
    af2[0] = *(const bf16x8*)&ub[r16*72 + 0*32 + g*8];
    af2[1] = *(const bf16x8*)&ub[r16*72 + 1*32 + g*8];
    f32x4 c2[11];
    #pragma unroll
    for(int s=0;s<11;s++) c2[s]=(f32x4){0,0,0,0};
    #pragma unroll
    for(int ks=0;ks<2;ks++){
      #pragma unroll
      for(int s=0;s<11;s++){
        bf16x8 bf = *(const bf16x8*)&sW2t[(s*16+r16)*72 + ks*32 + g*8];
        c2[s] = __builtin_amdgcn_mfma_f32_16x16x32_bf16(af2[ks],bf,c2[s],0,0,0);
      }
    }
    #pragma unroll
    for(int s=0;s<11;s++){
      int col = s*16 + r16;
      #pragma unroll
      for(int q=0;q<4;q++){
        wsb[(g*4+q)*WST + col] = (_Float16)(c2[s][q] + b2v[s]);
      }
    }
    // scatter rows to CSR slots
    int pv = 0;
    if(lane<16 && ebase+lane < E) pv = pos_of[ebase+lane];
    int rows = E - ebase; if(rows > 16) rows = 16;
    const float4* srcv = (const float4*)ub;
    int tot4 = rows*23;   // WST/8 float4 per row
    for(int i=lane; i<tot4; i+=64){
      int r = i/23, c = i - 23*r;
      int pos = __shfl(pv, r);
      ((float4*)(wbuf + (size_t)pos*WST))[c] = srcv[i];
    }
  }
}

// ---------- K3: geometric phase, CSR-sequential, shuffle-based ----------
// ck: x=ws1, y=(lane<48)?w2v_pre:0, z=scA, w=(lane<48)?cross_pre:scB[lane-48]
__global__ __launch_bounds__(256) void k_geo(
  const int* __restrict__ srcC, const int* __restrict__ dstC,
  const float4* __restrict__ eaC, const _Float16* __restrict__ wbuf,
  const float* __restrict__ adot,
  const float* __restrict__ xs_s, const float* __restrict__ xs_d,
  const float* __restrict__ xv_s, const float* __restrict__ xv_d,
  _Float16* __restrict__ cbuf, float* __restrict__ alphaC, int E)
{
  __shared__ float sAdot[80];
  __shared__ float sP[4][80];
  int t = threadIdx.x, wid = t>>6, lane = t&63;
  if(t<80) sAdot[t]=adot[t];
  __syncthreads();

  float* P = sP[wid];
  int nw = gridDim.x*4;
  const float inv_s3 = 0.5773502691896258f, inv_s2 = 0.7071067811865475f;

  int l3 = lane/3;
  int d  = lane - l3*3;
  int k3 = l3*3;
  int d1 = (d==2)?0:d+1;
  int d2 = (d==0)?2:d-1;
  int l3c = l3&15;                 // clamped for uniform loads
  int sA = (lane*3)&63, sB = (lane*3+1)&63, sC = (lane*3+2)&63;
  int cs1 = (k3+d1)&63, cs2 = (k3+d2)&63;
  int hh5 = (lane>>1)&7, st5 = hh5*10 + (lane&1)*5;
  float adl = sAdot[lane];
  float ad2 = sAdot[64+(lane&15)];

  for(int p = blockIdx.x*4+wid; p < E; p += nw){
    int si = srcC[p], di = dstC[p];
    float4 ea = eaC[p];
    const _Float16* wr = wbuf + (size_t)p*WST;
    float S = xs_s[(size_t)si*64+lane] + xs_d[(size_t)di*64+lane];
    float Vl = (lane<48) ? (xv_s[(size_t)si*48+lane] + xv_d[(size_t)di*48+lane]) : 0.f;
    float w0 = (float)wr[lane];
    float w1v = (float)wr[64+lane];
    float sc = w0*S*ea.x;
    float sg = 1.f/(1.f+__expf(-sc));
    P[lane] = sc*(0.2f + 0.8f*sg)*adl;
    // vd3/sc2 computed branchlessly (valid where used)
    float v0=__shfl(Vl,sA), v1=__shfl(Vl,sB), v2=__shfl(Vl,sC);
    float vd3 = v0*ea.y + v1*ea.z + v2*ea.w;
    float sc2 = (float)wr[144+(lane&15)]*vd3*inv_s3;
    if(lane<16){
      float sg2 = 1.f/(1.f+__expf(-sc2));
      P[64+lane] = sc2*(0.2f + 0.8f*sg2)*ad2;
    }
    // parallel head-sum: each lane sums 5, lanes<8 combine
    float s5 = P[st5] + P[st5+1] + P[st5+2] + P[st5+3] + P[st5+4];
    float aL = __shfl(s5, 2*(lane&7)) + __shfl(s5, 2*(lane&7)+1);
    if(lane<8) alphaC[(size_t)p*8+lane] = aL;
    // scB broadcast (full exec)
    float scBv = __shfl(sc2, lane&15);
    // pre-multiplied value components
    float Vd1 = __shfl(Vl, cs1), Vd2 = __shfl(Vl, cs2);
    float wslot = scBv;
    if(lane<48){
      float e1d1 = (d1==0)?ea.y:((d1==1)?ea.z:ea.w);
      float e1d2 = (d2==0)?ea.y:((d2==1)?ea.z:ea.w);
      float cr = Vd1*e1d2 - Vd2*e1d1;
      wslot = (float)wr[160+l3c]*cr*inv_s2;
    }
    float w2v_pre = (lane<48) ? (float)wr[128+l3c]*ea.x*Vl : 0.f;
    ushort4 ck;
    ck.x = f2h(w1v*S);
    ck.y = f2h(w2v_pre);
    ck.z = f2h(sc);
    ck.w = f2h(wslot);
    _Float16* cr_ = cbuf + (size_t)p*CROW;
    *(ushort4*)(cr_ + (size_t)lane*4) = ck;
    if(lane==0) *(float4*)((char*)cr_ + 512) = ea;
  }
}

// ---------- K4: softmax + aggregation + fused projections ----------
// pass 1.5 converts alphaC rows to ev in place -> pass 2 is pure loads+FMA.
// Projection weights live in LDS: the streaming cbuf traffic thrashes L1,
// so global weight reads cost L2 round-trips per node (R7-R11 plateau).
#define EDGE_PROC(b, ck_, ea_, w1x,w1y,w1z,sc,aa,xx) { \
  const float* ar_ = alphaC + (size_t)(b)*8; \
  float evW1_ = ar_[hW1], evSC_ = ar_[hSC], evA_ = ar_[hA], evX_ = ar_[hX]; \
  float ws1_ = h2f(ck_.x), scA_ = h2f(ck_.z), wv_ = h2f(ck_.w); \
  float vA_ = (lane<48) ? h2f(ck_.y) : wv_; \
  float t1_ = evW1_*ws1_; \
  w1x += t1_*ea_.y; w1y += t1_*ea_.z; w1z += t1_*ea_.w; \
  sc += evSC_*scA_; aa += evA_*vA_; xx += evX_*wv_; }

__global__ __launch_bounds__(256) void k_agg(
  const int* __restrict__ offs, float* __restrict__ alphaC,
  const _Float16* __restrict__ cbuf,
  const float* __restrict__ pws, const float* __restrict__ pbs,
  const float* __restrict__ pwv, float* __restrict__ out, int N)
{
  __shared__ float sWs[80*64];   // 20 KB
  __shared__ float sWv[96*16];   // 6 KB
  __shared__ float sPb[64];
  __shared__ float sVa[4][288];
  __shared__ float sSa[4][80];
  int t=threadIdx.x, wid=t>>6, lane=t&63;
  for(int i=t;i<80*64;i+=256) sWs[i]=pws[i];
  for(int i=t;i<96*16;i+=256) sWv[i]=pwv[i];
  if(t<64) sPb[t]=pbs[t];
  __syncthreads();

  float* Va = sVa[wid];
  float* Sa = sSa[wid];

  int l3 = lane/3;
  int d  = lane - l3*3;
  int hW1 = lane/12;
  int hX  = (80+l3)/12;
  int hSC = lane/10;
  int hA  = (lane<48) ? (64+l3)/12 : (64+(lane-48))/10;
  int h8 = lane&7;

  int nw4 = gridDim.x*4;
  for(int n = blockIdx.x*4+wid; n < N; n += nw4){
    int s0 = offs[n], s1 = offs[n+1];

    // pass 1: per-head max (lane l holds max of head l&7)
    float mx = -1e30f;
    for(int b = s0 + (lane>>3); b < s1; b += 8)
      mx = fmaxf(mx, alphaC[(size_t)b*8 + h8]);
    mx = fmaxf(mx, __shfl_xor(mx, 8));
    mx = fmaxf(mx, __shfl_xor(mx, 16));
    mx = fmaxf(mx, __shfl_xor(mx, 32));

    // pass 1.5: exp in place + den (8 exps per edge wave-wide)
    float dn = 0.f;
    for(int b = s0 + (lane>>3); b < s1; b += 8){
      size_t ix = (size_t)b*8 + h8;
      float ev = __expf(alphaC[ix] - mx);
      alphaC[ix] = ev;
      dn += ev;
    }
    dn += __shfl_xor(dn, 8);
    dn += __shfl_xor(dn, 16);
    dn += __shfl_xor(dn, 32);
    float rdn = 1.0f/(dn + 1e-9f);   // lane l: 1/den of head l&7
    float rW1 = __shfl(rdn, hW1);
    float rSC = __shfl(rdn, hSC);
    float rA  = __shfl(rdn, hA);
    float rX  = __shfl(rdn, hX);

    // pass 2: 4x-unrolled, 2 accumulator sets, pure FMA
    float w1xA=0.f,w1yA=0.f,w1zA=0.f,scAc=0.f,aaA=0.f,xxA=0.f;
    float w1xB=0.f,w1yB=0.f,w1zB=0.f,scBc=0.f,aaB=0.f,xxB=0.f;
    int b = s0;
    for(; b+3 < s1; b += 4){
      const _Float16* c0 = cbuf + (size_t)(b  )*CROW;
      const _Float16* c1 = cbuf + (size_t)(b+1)*CROW;
      const _Float16* c2 = cbuf + (size_t)(b+2)*CROW;
      const _Float16* c3 = cbuf + (size_t)(b+3)*CROW;
      ushort4 k0 = *(const ushort4*)(c0 + (size_t)lane*4);
      ushort4 k1 = *(const ushort4*)(c1 + (size_t)lane*4);
      ushort4 k2 = *(const ushort4*)(c2 + (size_t)lane*4);
      ushort4 k3v= *(const ushort4*)(c3 + (size_t)lane*4);
      float4 e0 = *(const float4*)((const char*)c0 + 512);
      float4 e1 = *(const float4*)((const char*)c1 + 512);
      float4 e2 = *(const float4*)((const char*)c2 + 512);
      float4 e3 = *(const float4*)((const char*)c3 + 512);
      EDGE_PROC(b,   k0, e0, w1xA,w1yA,w1zA,scAc,aaA,xxA)
      EDGE_PROC(b+1, k1, e1, w1xB,w1yB,w1zB,scBc,aaB,xxB)
      EDGE_PROC(b+2, k2, e2, w1xA,w1yA,w1zA,scAc,aaA,xxA)
      EDGE_PROC(b+3, k3v,e3, w1xB,w1yB,w1zB,scBc,aaB,xxB)
    }
    for(; b < s1; ++b){
      const _Float16* c0 = cbuf + (size_t)b*CROW;
      ushort4 k0 = *(const ushort4*)(c0 + (size_t)lane*4);
      float4 e0 = *(const float4*)((const char*)c0 + 512);
      EDGE_PROC(b, k0, e0, w1xA,w1yA,w1zA,scAc,aaA,xxA)
    }
    float w1x=w1xA+w1xB, w1y=w1yA+w1yB, w1z=w1zA+w1zB;
    float sc=scAc+scBc, aa=aaA+aaB, xx=xxA+xxB;

    Va[lane*3+0] = w1x*rW1;
    Va[lane*3+1] = w1y*rW1;
    Va[lane*3+2] = w1z*rW1;
    if(lane<48){
      Va[192+lane] = aa*rA;
      Va[240+lane] = xx*rX;
    } else {
      Sa[64+(lane-48)] = aa*rA;
    }
    Sa[lane] = sc*rSC;

    // fused projections (weights from LDS)
    float o1 = sPb[lane];
    #pragma unroll 8
    for(int i=0;i<80;i++) o1 += Sa[i]*sWs[i*64+lane];
    out[(size_t)n*112+lane] = o1;
    if(lane<48){
      float o2 = 0.f;
      #pragma unroll 8
      for(int k=0;k<64;k++) o2 += Va[k*3+d]*sWv[k*16+l3];
      #pragma unroll
      for(int k=0;k<16;k++) o2 += Va[192+k*3+d]*sWv[(64+k)*16+l3];
      #pragma unroll
      for(int k=0;k<16;k++) o2 += Va[240+k*3+d]*sWv[(80+k)*16+l3];
      out[(size_t)n*112+64+lane] = o2;
    }
  }
}

extern "C" void kernel_launch(void* const* d_in, const int* in_sizes, int n_in,
                              void* d_out, int out_size, void* d_ws, size_t ws_size,
                              hipStream_t stream)
{
  const int N = in_sizes[0]/112;
  const int E = in_sizes[1];
  const float* ni    = (const float*)d_in[0];
  const int*   esrc  = (const int*)d_in[1];
  const int*   edst  = (const int*)d_in[2];
  const float* eattr = (const float*)d_in[3];
  const float* escal = (const float*)d_in[4];
  const float* wss   = (const float*)d_in[5];
  const float* wsv   = (const float*)d_in[6];
  const float* wds   = (const float*)d_in[7];
  const float* wdv   = (const float*)d_in[8];
  const float* rw1   = (const float*)d_in[9];
  const float* rb1   = (const float*)d_in[10];
  const float* rw2   = (const float*)d_in[11];
  const float* rb2   = (const float*)d_in[12];
  const float* adot  = (const float*)d_in[13];
  const float* pws   = (const float*)d_in[14];
  const float* pbs   = (const float*)d_in[15];
  const float* pwv   = (const float*)d_in[16];
  float* out = (float*)d_out;

  char* ws = (char*)d_ws;
  size_t off = 0;
  auto alloc = [&](size_t bytes)->void*{
    void* p = ws + off;
    off = (off + bytes + 255) & ~(size_t)255;
    return p;
  };
  float*    xs_s  = (float*)   alloc((size_t)N*64*4);
  float*    xs_d  = (float*)   alloc((size_t)N*64*4);
  float*    xv_s  = (float*)   alloc((size_t)N*48*4);
  float*    xv_d  = (float*)   alloc((size_t)N*48*4);
  _Float16* wbuf  = (_Float16*)alloc((size_t)E*WST*2);
  _Float16* cbuf  = (_Float16*)alloc((size_t)E*CROW*2);
  float*    alphaC= (float*)   alloc((size_t)E*8*4);
  int*      pos_of= (int*)     alloc((size_t)E*4);
  int*      srcC  = (int*)     alloc((size_t)E*4);
  int*      dstC  = (int*)     alloc((size_t)E*4);
  float4*   eaC   = (float4*)  alloc((size_t)E*16);
  int*      deg   = (int*)     alloc((size_t)N*4);
  int*      offs  = (int*)     alloc((size_t)(N+1)*4);
  int*      cur   = (int*)     alloc((size_t)N*4);
  int*      bsum  = (int*)     alloc(256*4);

  const int nb = (N+255)/256;

  hipMemsetAsync(deg, 0, (size_t)N*4, stream);

  k_node<<<(N+63)/64, 256, 0, stream>>>(ni, wss, wsv, wds, wdv, xs_s, xs_d, xv_s, xv_d, N);
  k_deg<<<(E+255)/256, 256, 0, stream>>>(edst, deg, E);
  k_scan1<<<nb, 256, 0, stream>>>(deg, cur, bsum, N);
  k_scan2<<<1, 256, 0, stream>>>(bsum, offs, N, nb);
  k_scan3<<<nb, 256, 0, stream>>>(bsum, offs, cur, N);
  k_fill<<<(E+255)/256, 256, 0, stream>>>(esrc, edst, eattr, cur, pos_of, srcC, dstC, eaC, E);

  k_mlp<<<512, 256, 0, stream>>>(escal, rw1, rb1, rw2, rb2, pos_of, wbuf, E);

  k_geo<<<2048, 256, 0, stream>>>(srcC, dstC, eaC, wbuf, adot,
        xs_s, xs_d, xv_s, xv_d, cbuf, alphaC, E);

  k_agg<<<2048, 256, 0, stream>>>(offs, alphaC, cbuf, pws, pbs, pwv, out, N);
}